// Round 1
// baseline (284.516 us; speedup 1.0000x reference)
//
#include <hip/hip_runtime.h>
#include <math.h>

// Problem constants (from reference setup_inputs):
// B=16, C_in=32, C_out=32, H=256, W=256, K=16 frequencies.
// out[b,o,y,x] = (1/16)Re G[y,0] + (1/8) sum_{v=1..15} Re(G[y,v]) cos(2pi v x/256) - Im(G[y,v]) sin(2pi v x/256)
// G[y,v] = (1/16) sum_{u<16} blk[u,v] e^{+2pi i u y/256}
// blk[b,o,u,v] = sum_i S[b,i,u] * (Wr+iWi)[i,o,u,v]
// S[b,i,v] = (1/256) sum_w e^{-2pi i v w/256} * sum_h g[h] x[b,i,h,w],  g[h]=sum_{u<16} e^{-2pi i u h/256}

#define TWO_PI_OVER_256 0.02454369260617026  /* 2*pi/256 */

// ---------------- K1: S[b,i,v] from x ----------------
__global__ __launch_bounds__(256) void k1_spectral_sum(
    const float* __restrict__ x, float* __restrict__ s_re, float* __restrict__ s_im)
{
    __shared__ float twc[256], tws[256];     // cos/sin(2pi k/256)
    __shared__ float gre[256], gim[256];     // g[h]
    __shared__ float Pre[4][256], Pim[4][256];
    __shared__ float red_re[16][16], red_im[16][16];

    const int t = threadIdx.x;
    const int bi = blockIdx.x;               // b*32 + i

    {
        double a = TWO_PI_OVER_256 * (double)t;
        twc[t] = (float)cos(a);
        tws[t] = (float)sin(a);
    }
    __syncthreads();
    {
        float gr = 0.f, gi = 0.f;
        #pragma unroll
        for (int u = 0; u < 16; ++u) {
            int idx = (u * t) & 255;
            gr += twc[idx];
            gi -= tws[idx];
        }
        gre[t] = gr; gim[t] = gi;
    }
    __syncthreads();

    // Phase 1: P[w] = sum_h g[h]*x[h,w]; thread handles 4 columns, every 4th row.
    const float* img = x + (size_t)bi * 65536;
    const int cg = t & 63, rg = t >> 6;
    float4 pr = {0.f,0.f,0.f,0.f}, pi = {0.f,0.f,0.f,0.f};
    for (int h = rg; h < 256; h += 4) {
        const float4 xv = *(const float4*)(img + (h << 8) + (cg << 2));
        const float gr = gre[h], gi = gim[h];
        pr.x += gr * xv.x; pr.y += gr * xv.y; pr.z += gr * xv.z; pr.w += gr * xv.w;
        pi.x += gi * xv.x; pi.y += gi * xv.y; pi.z += gi * xv.z; pi.w += gi * xv.w;
    }
    *(float4*)&Pre[rg][cg << 2] = pr;
    *(float4*)&Pim[rg][cg << 2] = pi;
    __syncthreads();

    // Phase 2: S[v] = (1/256) sum_w P[w] e^{-2pi i v w/256}
    {
        const int v = t >> 4, j = t & 15;
        float ar = 0.f, ai = 0.f;
        #pragma unroll
        for (int m = 0; m < 16; ++m) {
            const int w = j + (m << 4);
            const float prr = Pre[0][w] + Pre[1][w] + Pre[2][w] + Pre[3][w];
            const float pii = Pim[0][w] + Pim[1][w] + Pim[2][w] + Pim[3][w];
            const int idx = (v * w) & 255;
            const float c = twc[idx], s = tws[idx];
            ar += prr * c + pii * s;     // Re((P)(c - i s))
            ai += pii * c - prr * s;     // Im
        }
        red_re[v][j] = ar; red_im[v][j] = ai;
    }
    __syncthreads();
    if (t < 16) {
        float ar = 0.f, ai = 0.f;
        #pragma unroll
        for (int j = 0; j < 16; ++j) { ar += red_re[t][j]; ai += red_im[t][j]; }
        s_re[bi * 16 + t] = ar * (1.0f / 256.0f);
        s_im[bi * 16 + t] = ai * (1.0f / 256.0f);
    }
}

// ---------------- K2: coefficients per (b,o,y) ----------------
__global__ __launch_bounds__(256) void k2_coef(
    const float* __restrict__ wr, const float* __restrict__ wi,
    const float* __restrict__ s_re, const float* __restrict__ s_im,
    float* __restrict__ coef)
{
    __shared__ float twc[256], tws[256];
    __shared__ float Sre[32][16], Sim[32][16];
    __shared__ float Br[256], Bi[256];       // blk[u*16+v]

    const int t = threadIdx.x;
    const int bo = blockIdx.x;               // b*32 + o
    const int b = bo >> 5, o = bo & 31;

    {
        double a = TWO_PI_OVER_256 * (double)t;
        twc[t] = (float)cos(a);
        tws[t] = (float)sin(a);
    }
    {
        const float* srp = s_re + b * 512;
        const float* sip = s_im + b * 512;
        ((float*)Sre)[t]       = srp[t];
        ((float*)Sre)[t + 256] = srp[t + 256];
        ((float*)Sim)[t]       = sip[t];
        ((float*)Sim)[t + 256] = sip[t + 256];
    }
    __syncthreads();

    // blk[u,v] = sum_i S[b,i,u] * W[i,o,u,v] (complex)
    {
        const int u = t >> 4;
        float br = 0.f, bim = 0.f;
        const float* wrp = wr + o * 256 + t;   // [i][o][u][v], u*16+v == t
        const float* wip = wi + o * 256 + t;
        #pragma unroll 8
        for (int i = 0; i < 32; ++i) {
            const float a_re = Sre[i][u], a_im = Sim[i][u];
            const float w_re = wrp[i * 8192], w_im = wip[i * 8192];
            br  += a_re * w_re - a_im * w_im;
            bim += a_re * w_im + a_im * w_re;
        }
        Br[t] = br; Bi[t] = bim;
    }
    __syncthreads();

    // G[y,v]: thread handles fixed v = t&15, 16 rows y = (t>>4)*16 + m
    {
        const int v = t & 15, yg = t >> 4;
        float br[16], bim[16];
        #pragma unroll
        for (int u = 0; u < 16; ++u) { br[u] = Br[u * 16 + v]; bim[u] = Bi[u * 16 + v]; }
        const float scale = (v == 0) ? (1.0f / 256.0f) : (1.0f / 128.0f);
        for (int m = 0; m < 16; ++m) {
            const int y = yg * 16 + m;
            const float c1 = twc[y], s1 = tws[y];   // e^{+2pi i y/256}
            float gr = br[0], gi = bim[0];
            float cc = 1.f, cs = 0.f;
            #pragma unroll
            for (int u = 1; u < 16; ++u) {
                const float nc = cc * c1 - cs * s1;
                const float ns = cc * s1 + cs * c1;
                cc = nc; cs = ns;
                gr += br[u] * cc - bim[u] * cs;
                gi += br[u] * cs + bim[u] * cc;
            }
            float* cp = coef + (((size_t)bo * 256 + y) << 5);
            cp[v]      = gr * scale;
            cp[16 + v] = (v == 0) ? 0.f : (-gi * scale);
        }
    }
}

// ---------------- K3: synthesis out[b,o,y,x] ----------------
__global__ __launch_bounds__(256) void k3_synth(
    const float* __restrict__ coef, float* __restrict__ out)
{
    __shared__ float twc[256], tws[256];
    const int t = threadIdx.x;
    const int blk = blockIdx.x;
    const int bo = blk >> 2;
    const int y0 = (blk & 3) << 6;

    {
        double a = TWO_PI_OVER_256 * (double)t;
        twc[t] = (float)cos(a);
        tws[t] = (float)sin(a);
    }
    __syncthreads();

    float c[16], s[16];
    #pragma unroll
    for (int v = 0; v < 16; ++v) {
        const int idx = (v * t) & 255;
        c[v] = twc[idx];
        s[v] = tws[idx];
    }
    s[0] = 0.f;

    const float* cp = coef + ((size_t)bo * 256 + y0) * 32;   // wave-uniform -> s_load
    float* op = out + (size_t)bo * 65536 + (size_t)y0 * 256 + t;
    for (int yy = 0; yy < 64; ++yy) {
        const float* p = cp + yy * 32;
        float acc = 0.f;
        #pragma unroll
        for (int v = 0; v < 16; ++v) {
            acc += p[v] * c[v];
            acc += p[v + 16] * s[v];
        }
        op[yy * 256] = acc;
    }
}

extern "C" void kernel_launch(void* const* d_in, const int* in_sizes, int n_in,
                              void* d_out, int out_size, void* d_ws, size_t ws_size,
                              hipStream_t stream) {
    (void)in_sizes; (void)n_in; (void)out_size; (void)ws_size;
    const float* x  = (const float*)d_in[0];
    const float* wr = (const float*)d_in[1];
    const float* wi = (const float*)d_in[2];
    float* out  = (float*)d_out;
    float* s_re = (float*)d_ws;            // 512*16 floats
    float* s_im = s_re + 8192;             // 512*16 floats
    float* coef = s_im + 8192;             // 512*256*32 floats = 16 MB

    k1_spectral_sum<<<512, 256, 0, stream>>>(x, s_re, s_im);
    k2_coef<<<512, 256, 0, stream>>>(wr, wi, s_re, s_im, coef);
    k3_synth<<<2048, 256, 0, stream>>>(coef, out);
}

// Round 2
// 279.180 us; speedup vs baseline: 1.0191x; 1.0191x over previous
//
#include <hip/hip_runtime.h>
#include <math.h>

// B=16, C_in=32, C_out=32, H=256, W=256, K=16.
// S[b,i,v]   = (1/256) sum_w e^{-2pi i v w/256} * sum_h g[h] x[b,i,h,w],  g[h]=sum_{u<16} e^{-2pi i u h/256}
// blk[b,o,u,v] = sum_i S[b,i,u] * (Wr+iWi)[i,o,u,v]
// G[y,v]     = sum_u blk[u,v] e^{+2pi i u y/256}
// out[b,o,y,x] = (1/256)Re G[y,0] + (1/128) sum_{v=1..15} Re(G[y,v]) cos(2pi v x/256) - Im(G[y,v]) sin(2pi v x/256)

#define TWO_PI_OVER_256 0.02454369260617026 /* 2*pi/256 */

// ---------------- K1: partial S over 64-row chunks ----------------
// grid = 512 (b*32+i) x 4 chunks = 2048 blocks.
// s_part layout: [bi][chunk][32] floats: [0..15]=Re S_partial, [16..31]=Im.
__global__ __launch_bounds__(256) void k1_partial(
    const float* __restrict__ x, float* __restrict__ s_part)
{
    __shared__ float twc[256], tws[256];
    __shared__ float gre[64], gim[64];
    __shared__ float Pre[4][256], Pim[4][256];
    __shared__ float red_re[16][16], red_im[16][16];

    const int t = threadIdx.x;
    const int blk = blockIdx.x;
    const int bi = blk >> 2, chunk = blk & 3;
    const int y0 = chunk << 6;

    {
        double a = TWO_PI_OVER_256 * (double)t;
        twc[t] = (float)cos(a);
        tws[t] = (float)sin(a);
    }
    __syncthreads();
    if (t < 64) {
        const int h = y0 + t;
        float gr = 0.f, gi = 0.f;
        #pragma unroll
        for (int u = 0; u < 16; ++u) {
            const int idx = (u * h) & 255;
            gr += twc[idx];
            gi -= tws[idx];
        }
        gre[t] = gr; gim[t] = gi;
    }
    __syncthreads();

    // Phase 1: partial P[w] = sum over 64 rows of g[h]*x[h,w]
    const float* img = x + (size_t)bi * 65536 + (size_t)y0 * 256;
    const int cg = t & 63, rg = t >> 6;
    float4 pr = {0.f,0.f,0.f,0.f}, pi = {0.f,0.f,0.f,0.f};
    #pragma unroll 4
    for (int k = 0; k < 16; ++k) {
        const int hl = rg + (k << 2);
        const float4 xv = *(const float4*)(img + (hl << 8) + (cg << 2));
        const float gr = gre[hl], gi = gim[hl];
        pr.x += gr * xv.x; pr.y += gr * xv.y; pr.z += gr * xv.z; pr.w += gr * xv.w;
        pi.x += gi * xv.x; pi.y += gi * xv.y; pi.z += gi * xv.z; pi.w += gi * xv.w;
    }
    *(float4*)&Pre[rg][cg << 2] = pr;
    *(float4*)&Pim[rg][cg << 2] = pi;
    __syncthreads();

    // Phase 2: S_partial[v] = (1/256) sum_w P[w] e^{-2pi i v w/256}
    {
        const int v = t >> 4, j = t & 15;
        float ar = 0.f, ai = 0.f;
        #pragma unroll
        for (int m = 0; m < 16; ++m) {
            const int w = j + (m << 4);
            const float prr = Pre[0][w] + Pre[1][w] + Pre[2][w] + Pre[3][w];
            const float pii = Pim[0][w] + Pim[1][w] + Pim[2][w] + Pim[3][w];
            const int idx = (v * w) & 255;
            const float c = twc[idx], s = tws[idx];
            ar += prr * c + pii * s;
            ai += pii * c - prr * s;
        }
        red_re[v][j] = ar; red_im[v][j] = ai;
    }
    __syncthreads();
    if (t < 16) {
        float ar = 0.f, ai = 0.f;
        #pragma unroll
        for (int j = 0; j < 16; ++j) { ar += red_re[t][j]; ai += red_im[t][j]; }
        float* sp = s_part + (size_t)bi * 128 + chunk * 32;
        sp[t]      = ar * (1.0f / 256.0f);
        sp[t + 16] = ai * (1.0f / 256.0f);
    }
}

// ---------------- K23: blk + G-coefs + synthesis, fused ----------------
// grid = 512 (b*32+o) x 4 row-chunks = 2048 blocks, 64 rows each.
__global__ __launch_bounds__(256) void k23_synth(
    const float* __restrict__ wr, const float* __restrict__ wi,
    const float* __restrict__ s_part, float* __restrict__ out)
{
    __shared__ float twc[256], tws[256];
    __shared__ float Sre[32][16], Sim[32][16];
    __shared__ float Br[256], Bi[256];
    __shared__ __align__(16) float coef[64][36];  // [row][0..15]=cos-co, [16..31]=sin-co; stride 36 (144B, 16B-aligned, bank-spread)

    const int t = threadIdx.x;
    const int blk = blockIdx.x;
    const int bo = blk >> 2;
    const int y0 = (blk & 3) << 6;
    const int b = bo >> 5, o = bo & 31;

    {
        double a = TWO_PI_OVER_256 * (double)t;
        twc[t] = (float)cos(a);
        tws[t] = (float)sin(a);
    }
    // Load + sum the 4 S partials. 512 (i,u) pairs / 256 threads = 2 each.
    {
        const float* sb = s_part + (size_t)b * 4096;
        #pragma unroll
        for (int e = t; e < 512; e += 256) {
            const int i = e >> 4, u = e & 15;
            const float* p = sb + i * 128 + u;
            Sre[i][u] = p[0] + p[32] + p[64] + p[96];
            Sim[i][u] = p[16] + p[48] + p[80] + p[112];
        }
    }
    __syncthreads();

    // blk[u,v] = sum_i S[b,i,u] * W[i,o,u,v] (complex); t == u*16+v
    {
        const int u = t >> 4;
        float br = 0.f, bim = 0.f;
        const float* wrp = wr + o * 256 + t;   // [i][o][u][v]
        const float* wip = wi + o * 256 + t;
        #pragma unroll 8
        for (int i = 0; i < 32; ++i) {
            const float a_re = Sre[i][u], a_im = Sim[i][u];
            const float w_re = wrp[i * 8192], w_im = wip[i * 8192];
            br  += a_re * w_re - a_im * w_im;
            bim += a_re * w_im + a_im * w_re;
        }
        Br[t] = br; Bi[t] = bim;
    }
    __syncthreads();

    // G rows for this chunk: thread (v = t&15, slot = t>>4) handles rows slot*4+m.
    {
        const int v = t & 15, slot = t >> 4;
        float br[16], bim[16];
        #pragma unroll
        for (int u = 0; u < 16; ++u) { br[u] = Br[u * 16 + v]; bim[u] = Bi[u * 16 + v]; }
        const float scale = (v == 0) ? (1.0f / 256.0f) : (1.0f / 128.0f);
        #pragma unroll
        for (int m = 0; m < 4; ++m) {
            const int r = slot * 4 + m;
            const int y = y0 + r;
            const float c1 = twc[y], s1 = tws[y];   // e^{+2pi i y/256}
            float gr = br[0], gi = bim[0];
            float cc = 1.f, cs = 0.f;
            #pragma unroll
            for (int u = 1; u < 16; ++u) {
                const float nc = cc * c1 - cs * s1;
                const float ns = cc * s1 + cs * c1;
                cc = nc; cs = ns;
                gr += br[u] * cc - bim[u] * cs;
                gi += br[u] * cs + bim[u] * cc;
            }
            coef[r][v]      = gr * scale;
            coef[r][16 + v] = (v == 0) ? 0.f : (-gi * scale);
        }
    }
    __syncthreads();

    // Synthesis: thread = column x = t; 64 rows; trig in registers, coef via b128 broadcast.
    float c[16], s[16];
    #pragma unroll
    for (int v = 0; v < 16; ++v) {
        const int idx = (v * t) & 255;
        c[v] = twc[idx];
        s[v] = tws[idx];
    }
    s[0] = 0.f;

    float* op = out + (size_t)bo * 65536 + (size_t)y0 * 256 + t;
    #pragma unroll 2
    for (int r = 0; r < 64; ++r) {
        const float4* crow = (const float4*)&coef[r][0];
        float acc = 0.f;
        #pragma unroll
        for (int q = 0; q < 4; ++q) {
            const float4 pc = crow[q];
            acc += pc.x * c[q*4+0] + pc.y * c[q*4+1] + pc.z * c[q*4+2] + pc.w * c[q*4+3];
        }
        #pragma unroll
        for (int q = 0; q < 4; ++q) {
            const float4 ps = crow[4+q];
            acc += ps.x * s[q*4+0] + ps.y * s[q*4+1] + ps.z * s[q*4+2] + ps.w * s[q*4+3];
        }
        op[r * 256] = acc;
    }
}

extern "C" void kernel_launch(void* const* d_in, const int* in_sizes, int n_in,
                              void* d_out, int out_size, void* d_ws, size_t ws_size,
                              hipStream_t stream) {
    (void)in_sizes; (void)n_in; (void)out_size; (void)ws_size;
    const float* x  = (const float*)d_in[0];
    const float* wr = (const float*)d_in[1];
    const float* wi = (const float*)d_in[2];
    float* out    = (float*)d_out;
    float* s_part = (float*)d_ws;          // 512 * 128 floats = 256 KB

    k1_partial<<<2048, 256, 0, stream>>>(x, s_part);
    k23_synth<<<2048, 256, 0, stream>>>(wr, wi, s_part, out);
}